// Round 1
// baseline (265.551 us; speedup 1.0000x reference)
//
#include <hip/hip_runtime.h>

#define DEVFN __device__ __forceinline__

DEVFN float fast_exp2(float x) {
#if __has_builtin(__builtin_amdgcn_exp2f)
  return __builtin_amdgcn_exp2f(x);
#else
  return exp2f(x);
#endif
}
DEVFN float fast_rcp(float x) {
#if __has_builtin(__builtin_amdgcn_rcpf)
  return __builtin_amdgcn_rcpf(x);
#else
  return 1.0f / x;
#endif
}

constexpr int S = 512, B = 8192, I = 2, H = 5, G = 4 * H;
constexpr float KN1 = -1.44269504088896340736f;   // -log2(e)
constexpr float KN2 = 2.0f * KN1;                 // -2*log2(e)

// One thread = one batch element's full 512-step recurrence.
// Gate order (PyTorch): rows [0:5)=i, [5:10)=f, [10:15)=g, [15:20)=o.
// Weights/biases pre-scaled so activations need only exp2+rcp:
//   sigmoid(z) = rcp(1 + exp2(-z*log2e))          (acc holds -z*log2e)
//   tanh(z)    = 2*rcp(1 + exp2(-2z*log2e)) - 1   (acc holds -2z*log2e)
__global__ __launch_bounds__(64, 1) void lstm_kernel(
    const float* __restrict__ x,      // [S,B,I]
    const float* __restrict__ W_ih,   // [G,I]
    const float* __restrict__ W_hh,   // [G,H]
    const float* __restrict__ b_ih,   // [G]
    const float* __restrict__ b_hh,   // [G]
    const float* __restrict__ W_lin,  // [1,H]
    const float* __restrict__ b_lin,  // [1]
    float* __restrict__ out)          // [B,1]
{
  const int b = blockIdx.x * blockDim.x + threadIdx.x;

  // Load + pre-scale weights into registers (loop-invariant, uniform).
  float wi0[G], wi1[G], wh[G][H], bb[G];
  #pragma unroll
  for (int g = 0; g < G; ++g) {
    const float s = (g >= 2 * H && g < 3 * H) ? KN2 : KN1;  // g-gate rows get -2log2e
    wi0[g] = W_ih[g * I + 0] * s;
    wi1[g] = W_ih[g * I + 1] * s;
    #pragma unroll
    for (int j = 0; j < H; ++j) wh[g][j] = W_hh[g * H + j] * s;
    bb[g] = (b_ih[g] + b_hh[g]) * s;
  }

  float h[H], c[H];
  #pragma unroll
  for (int j = 0; j < H; ++j) { h[j] = 0.0f; c[j] = 0.0f; }

  const float2* __restrict__ x2 = (const float2*)x;

  auto step = [&](float2 xv) {
    float a[G];
    #pragma unroll
    for (int g = 0; g < G; ++g) {
      float t = fmaf(xv.x, wi0[g], bb[g]);
      t = fmaf(xv.y, wi1[g], t);
      #pragma unroll
      for (int j = 0; j < H; ++j) t = fmaf(h[j], wh[g][j], t);
      a[g] = t;
    }
    #pragma unroll
    for (int j = 0; j < H; ++j) {
      float iv = fast_rcp(1.0f + fast_exp2(a[j]));
      float fv = fast_rcp(1.0f + fast_exp2(a[H + j]));
      float gv = fmaf(2.0f, fast_rcp(1.0f + fast_exp2(a[2 * H + j])), -1.0f);
      float ov = fast_rcp(1.0f + fast_exp2(a[3 * H + j]));
      float cv = fmaf(fv, c[j], iv * gv);
      c[j] = cv;
      float th = fmaf(2.0f, fast_rcp(1.0f + fast_exp2(cv * KN2)), -1.0f);
      h[j] = ov * th;
    }
  };

  // Ping-pong register prefetch: 4 timesteps ahead (~2400 cy of compute)
  // fully hides ~900 cy cold HBM latency of the per-step x load.
  constexpr int CH = 4;
  float2 buf0[CH], buf1[CH];

  #pragma unroll
  for (int u = 0; u < CH; ++u) buf0[u] = x2[(size_t)u * B + b];

  for (int t0 = 0; t0 < S; t0 += 2 * CH) {
    #pragma unroll
    for (int u = 0; u < CH; ++u) buf1[u] = x2[(size_t)(t0 + CH + u) * B + b];
    #pragma unroll
    for (int u = 0; u < CH; ++u) step(buf0[u]);
    if (t0 + 2 * CH < S) {
      #pragma unroll
      for (int u = 0; u < CH; ++u) buf0[u] = x2[(size_t)(t0 + 2 * CH + u) * B + b];
    }
    #pragma unroll
    for (int u = 0; u < CH; ++u) step(buf1[u]);
  }

  // Final linear: out[b] = h_last @ W_lin^T + b_lin
  float o = b_lin[0];
  #pragma unroll
  for (int j = 0; j < H; ++j) o = fmaf(h[j], W_lin[j], o);
  out[b] = o;
}

extern "C" void kernel_launch(void* const* d_in, const int* in_sizes, int n_in,
                              void* d_out, int out_size, void* d_ws, size_t ws_size,
                              hipStream_t stream) {
  const float* x     = (const float*)d_in[0];
  const float* W_ih  = (const float*)d_in[1];
  const float* W_hh  = (const float*)d_in[2];
  const float* b_ih  = (const float*)d_in[3];
  const float* b_hh  = (const float*)d_in[4];
  const float* W_lin = (const float*)d_in[5];
  const float* b_lin = (const float*)d_in[6];
  float* out = (float*)d_out;

  dim3 grid(B / 64), block(64);
  hipLaunchKernelGGL(lstm_kernel, grid, block, 0, stream,
                     x, W_ih, W_hh, b_ih, b_hh, W_lin, b_lin, out);
}

// Round 2
// 85.060 us; speedup vs baseline: 3.1219x; 3.1219x over previous
//
#include <hip/hip_runtime.h>

constexpr int S = 512, B = 8192, H = 5;
constexpr float KN1 = -1.44269504088896340736f;   // -log2(e)
constexpr float KN2 = 2.0f * KN1;                 // -2*log2(e)

__device__ __forceinline__ float fexp2(float x) { return __builtin_amdgcn_exp2f(x); }
__device__ __forceinline__ float frcp(float x)  { return __builtin_amdgcn_rcpf(x); }

// ds_swizzle BitMode: src_lane = ((lane & and) | or) ^ xor ; offset = xor<<10 | or<<5 | and
// Broadcast lane k of each 8-lane group: and=0x18, or=k      -> 0x018 + (k<<5)
// Butterfly xor k within 32-half:        and=0x1f, xor=k     -> (k<<10) | 0x1f
#define SWZ(v, imm) __int_as_float(__builtin_amdgcn_ds_swizzle(__float_as_int(v), (imm)))

// 8 lanes per batch chain; lane j in [0,5) owns hidden unit j (its i,f,g,o
// gates + c_j/h_j). Lanes 5..7 duplicate unit 4 (valid loads, unused results).
// 8192 chains * 8 = 65536 threads = 1024 waves = 1 wave per SIMD machine-wide.
// Weights pre-scaled by -log2(e) (or -2log2(e) for tanh args) so every
// activation is exp2 + add + rcp (+ fma for tanh).
__global__ __launch_bounds__(256, 1) void lstm_kernel(
    const float* __restrict__ x,      // [S,B,2]
    const float* __restrict__ W_ih,   // [4H,2]
    const float* __restrict__ W_hh,   // [4H,H]
    const float* __restrict__ b_ih,   // [4H]
    const float* __restrict__ b_hh,   // [4H]
    const float* __restrict__ W_lin,  // [1,H]
    const float* __restrict__ b_lin,  // [1]
    float* __restrict__ out)          // [B,1]
{
  const int tid   = blockIdx.x * blockDim.x + threadIdx.x;
  const int chain = tid >> 3;          // batch element
  const int j     = tid & 7;           // lane-in-group
  const int jm    = (j < H) ? j : H - 1;

  // Per-lane weights: gate type t=0..3 (i,f,g,o), row g = t*H + jm.
  float wi0[4], wi1[4], wh[4][H], bb[4];
  #pragma unroll
  for (int t = 0; t < 4; ++t) {
    const int g = t * H + jm;
    const float s = (t == 2) ? KN2 : KN1;
    wi0[t] = W_ih[g * 2 + 0] * s;
    wi1[t] = W_ih[g * 2 + 1] * s;
    #pragma unroll
    for (int k = 0; k < H; ++k) wh[t][k] = W_hh[g * H + k] * s;
    bb[t] = (b_ih[g] + b_hh[g]) * s;
  }

  float h = 0.0f, c = 0.0f;            // this lane's unit state
  float hg[H] = {0, 0, 0, 0, 0};       // gathered h vector (all lanes)

  const float2* __restrict__ x2 = (const float2*)x;

  auto step = [&](float2 xv) {
    float a[4];
    #pragma unroll
    for (int t = 0; t < 4; ++t) {
      float v = fmaf(xv.x, wi0[t], bb[t]);
      v = fmaf(xv.y, wi1[t], v);
      #pragma unroll
      for (int k = 0; k < H; ++k) v = fmaf(hg[k], wh[t][k], v);
      a[t] = v;
    }
    const float iv = frcp(1.0f + fexp2(a[0]));
    const float fv = frcp(1.0f + fexp2(a[1]));
    const float gv = fmaf(2.0f, frcp(1.0f + fexp2(a[2])), -1.0f);
    const float ov = frcp(1.0f + fexp2(a[3]));
    c = fmaf(fv, c, iv * gv);
    const float th = fmaf(2.0f, frcp(1.0f + fexp2(c * KN2)), -1.0f);
    h = ov * th;
    // Broadcast each unit's h to all 8 lanes of the group.
    hg[0] = SWZ(h, 0x018);
    hg[1] = SWZ(h, 0x038);
    hg[2] = SWZ(h, 0x058);
    hg[3] = SWZ(h, 0x078);
    hg[4] = SWZ(h, 0x098);
  };

  // Ping-pong register prefetch of x, 4 steps deep (all 8 lanes of a group
  // load the same 8B -> one 64B line per wave per step, L1-friendly).
  constexpr int CH = 4;
  float2 buf0[CH], buf1[CH];
  #pragma unroll
  for (int u = 0; u < CH; ++u) buf0[u] = x2[(size_t)u * B + chain];

  for (int t0 = 0; t0 < S; t0 += 2 * CH) {
    #pragma unroll
    for (int u = 0; u < CH; ++u) buf1[u] = x2[(size_t)(t0 + CH + u) * B + chain];
    #pragma unroll
    for (int u = 0; u < CH; ++u) step(buf0[u]);
    if (t0 + 2 * CH < S) {
      #pragma unroll
      for (int u = 0; u < CH; ++u) buf0[u] = x2[(size_t)(t0 + 2 * CH + u) * B + chain];
    }
    #pragma unroll
    for (int u = 0; u < CH; ++u) step(buf1[u]);
  }

  // out[chain] = sum_j h_j * W_lin[j] + b_lin  (tree-reduce within the group)
  float p = (j < H) ? h * W_lin[jm] : 0.0f;
  p += SWZ(p, 0x41F);    // xor 1
  p += SWZ(p, 0x81F);    // xor 2
  p += SWZ(p, 0x101F);   // xor 4
  if (j == 0) out[chain] = p + b_lin[0];
}

extern "C" void kernel_launch(void* const* d_in, const int* in_sizes, int n_in,
                              void* d_out, int out_size, void* d_ws, size_t ws_size,
                              hipStream_t stream) {
  const float* x     = (const float*)d_in[0];
  const float* W_ih  = (const float*)d_in[1];
  const float* W_hh  = (const float*)d_in[2];
  const float* b_ih  = (const float*)d_in[3];
  const float* b_hh  = (const float*)d_in[4];
  const float* W_lin = (const float*)d_in[5];
  const float* b_lin = (const float*)d_in[6];
  float* out = (float*)d_out;

  const int threads = B * 8;           // 65536
  dim3 grid(threads / 256), block(256);
  hipLaunchKernelGGL(lstm_kernel, grid, block, 0, stream,
                     x, W_ih, W_hh, b_ih, b_hh, W_lin, b_lin, out);
}

// Round 3
// 81.539 us; speedup vs baseline: 3.2567x; 1.0432x over previous
//
#include <hip/hip_runtime.h>

constexpr int S = 512, B = 8192, H = 5;
constexpr float KN1 = -1.44269504088896340736f;   // -log2(e)
constexpr float KN2 = 2.0f * KN1;                 // -2*log2(e)

__device__ __forceinline__ float fexp2(float x) { return __builtin_amdgcn_exp2f(x); }
__device__ __forceinline__ float frcp(float x)  { return __builtin_amdgcn_rcpf(x); }

// ds_swizzle BitMode: src = ((lane & and) | or) ^ xor ; offset = xor<<10 | or<<5 | and
// Broadcast lane (8+k) within each 16-lane group: and=0x10, or=8+k -> ((8+k)<<5)|0x10
// Butterfly xor k: and=0x1f, xor=k -> (k<<10)|0x1f
#define SWZ(v, imm) __int_as_float(__builtin_amdgcn_ds_swizzle(__float_as_int(v), (imm)))
// DPP row_ror:8 (within 16-lane rows): lane l receives lane (l+8)&15. VALU-pipe xor8.
#define ROR8(v) __int_as_float(__builtin_amdgcn_mov_dpp(__float_as_int(v), 0x128, 0xF, 0xF, false))

// 16 lanes per batch chain: lane = u*8 + j, u in {0,1}, j in [0,8) (j>=5 dups unit 4).
//   u=0 lane j computes gates i_j and g_j; u=1 lane j computes f_j and o_j.
//   Cell state c_j and h_j live on u=1 lanes.
// 8192 chains * 16 = 131072 threads = 2048 waves = 2 waves/SIMD (latency hiding).
// One exp2+rcp pair activates i(u0)+f(u1) together; another g(u0)+o(u1) with
// per-lane epilogue constants. Weights pre-scaled by -log2(e) / -2log2(e).
__global__ __launch_bounds__(256, 2) void lstm_kernel(
    const float* __restrict__ x,      // [S,B,2]
    const float* __restrict__ W_ih,   // [4H,2]
    const float* __restrict__ W_hh,   // [4H,H]
    const float* __restrict__ b_ih,   // [4H]
    const float* __restrict__ b_hh,   // [4H]
    const float* __restrict__ W_lin,  // [1,H]
    const float* __restrict__ b_lin,  // [1]
    float* __restrict__ out)          // [B,1]
{
  const int tid   = blockIdx.x * blockDim.x + threadIdx.x;
  const int chain = tid >> 4;          // batch element
  const int l     = tid & 15;
  const int u     = l >> 3;            // 0: i,g   1: f,o
  const int j     = l & 7;
  const int jm    = (j < H) ? j : H - 1;

  // Row for "act1" (sigmoid: i or f) and "act2" (g: tanh-arg, or o: sigmoid).
  const int r1 = (u ? H : 0) + jm;
  const int r2 = (u ? 3 * H : 2 * H) + jm;
  const float s2 = u ? KN1 : KN2;
  const float eA = u ? 1.0f : 2.0f;    // act2 epilogue: g = 2r-1, o = r
  const float eB = u ? 0.0f : -1.0f;

  float w1x0 = W_ih[r1 * 2 + 0] * KN1, w1x1 = W_ih[r1 * 2 + 1] * KN1;
  float w2x0 = W_ih[r2 * 2 + 0] * s2,  w2x1 = W_ih[r2 * 2 + 1] * s2;
  float w1h[H], w2h[H];
  #pragma unroll
  for (int k = 0; k < H; ++k) {
    w1h[k] = W_hh[r1 * H + k] * KN1;
    w2h[k] = W_hh[r2 * H + k] * s2;
  }
  const float b1 = (b_ih[r1] + b_hh[r1]) * KN1;
  const float b2 = (b_ih[r2] + b_hh[r2]) * s2;

  float h = 0.0f, c = 0.0f;            // valid on u=1 lanes
  float hg[H] = {0, 0, 0, 0, 0};

  const float2* __restrict__ x2 = (const float2*)x;

  auto step = [&](float2 xv) {
    float a1 = fmaf(xv.x, w1x0, b1);
    a1 = fmaf(xv.y, w1x1, a1);
    float a2 = fmaf(xv.x, w2x0, b2);
    a2 = fmaf(xv.y, w2x1, a2);
    #pragma unroll
    for (int k = 0; k < H; ++k) {
      a1 = fmaf(hg[k], w1h[k], a1);
      a2 = fmaf(hg[k], w2h[k], a2);
    }
    const float v1 = frcp(1.0f + fexp2(a1));          // i (u0) / f (u1)
    const float r2v = frcp(1.0f + fexp2(a2));
    const float go = fmaf(r2v, eA, eB);               // g (u0) / o (u1)
    const float p  = v1 * go;                         // i*g (u0) / junk (u1)
    const float pr = ROR8(p);                         // u1 receives i*g
    c = fmaf(v1, c, pr);                              // f*c + i*g  (valid on u1)
    const float th = fmaf(2.0f, frcp(1.0f + fexp2(c * KN2)), -1.0f);
    h = go * th;                                      // o * tanh(c) on u1
    // Broadcast h_k (on u1 lane 8+k) to all 16 lanes of the group.
    hg[0] = SWZ(h, 0x110);
    hg[1] = SWZ(h, 0x130);
    hg[2] = SWZ(h, 0x150);
    hg[3] = SWZ(h, 0x170);
    hg[4] = SWZ(h, 0x190);
  };

  // Ping-pong register prefetch of x, 4 steps deep.
  constexpr int CH = 4;
  float2 buf0[CH], buf1[CH];
  #pragma unroll
  for (int t = 0; t < CH; ++t) buf0[t] = x2[(size_t)t * B + chain];

  for (int t0 = 0; t0 < S; t0 += 2 * CH) {
    #pragma unroll
    for (int t = 0; t < CH; ++t) buf1[t] = x2[(size_t)(t0 + CH + t) * B + chain];
    #pragma unroll
    for (int t = 0; t < CH; ++t) step(buf0[t]);
    if (t0 + 2 * CH < S) {
      #pragma unroll
      for (int t = 0; t < CH; ++t) buf0[t] = x2[(size_t)(t0 + 2 * CH + t) * B + chain];
    }
    #pragma unroll
    for (int t = 0; t < CH; ++t) step(buf1[t]);
  }

  // out[chain] = sum_j h_j * W_lin[j] + b_lin; h_j on u1 lane 8+j.
  float p = (u == 1 && j < H) ? h * W_lin[jm] : 0.0f;
  p += SWZ(p, 0x41F);    // xor 1
  p += SWZ(p, 0x81F);    // xor 2
  p += SWZ(p, 0x101F);   // xor 4
  if ((tid & 15) == 8) out[chain] = p + b_lin[0];
}

extern "C" void kernel_launch(void* const* d_in, const int* in_sizes, int n_in,
                              void* d_out, int out_size, void* d_ws, size_t ws_size,
                              hipStream_t stream) {
  const float* x     = (const float*)d_in[0];
  const float* W_ih  = (const float*)d_in[1];
  const float* W_hh  = (const float*)d_in[2];
  const float* b_ih  = (const float*)d_in[3];
  const float* b_hh  = (const float*)d_in[4];
  const float* W_lin = (const float*)d_in[5];
  const float* b_lin = (const float*)d_in[6];
  float* out = (float*)d_out;

  const int threads = B * 16;          // 131072 -> 2048 waves -> 2/SIMD
  dim3 grid(threads / 256), block(256);
  hipLaunchKernelGGL(lstm_kernel, grid, block, 0, stream,
                     x, W_ih, W_hh, b_ih, b_hh, W_lin, b_lin, out);
}